// Round 1
// baseline (457.529 us; speedup 1.0000x reference)
//
#include <hip/hip_runtime.h>
#include <hip/hip_bf16.h>
#include <stdint.h>

#define BB 32
#define TT 4096
#define DD 64
#define SS 128
#define HH 512

#define CH_L 256
#define CH_W 64
#define NCHUNK (TT / CH_L)

typedef __attribute__((ext_vector_type(4))) float f32x4;
typedef __attribute__((ext_vector_type(8))) short s16x8;
typedef __attribute__((ext_vector_type(4))) short s16x4;

__device__ __forceinline__ ushort f2bfu(float x) {
    uint32_t b = __float_as_uint(x);
    uint32_t r = (b + 0x7FFFu + ((b >> 16) & 1u)) >> 16;
    return (ushort)r;
}
__device__ __forceinline__ float bfu2f(ushort u) {
    return __uint_as_float(((uint32_t)u) << 16);
}

// ---------------------------------------------------------------------------
// Prep: PfT[s][i] = softmax_row_i(trans)[s]; PbT[s][i] = softmax_col_i(trans)[s]
// (transposed so scan thread s reads its column contiguously)
// ---------------------------------------------------------------------------
__global__ void prep_trans(const float* __restrict__ tr,
                           float* __restrict__ PfT, float* __restrict__ PbT) {
    int j = threadIdx.x;  // 0..127
    // backward: column-j stats (log_softmax over rows of column j)
    float cm = -1e30f;
    for (int s = 0; s < SS; ++s) cm = fmaxf(cm, tr[s * SS + j]);
    float cs = 0.f;
    for (int s = 0; s < SS; ++s) cs += __expf(tr[s * SS + j] - cm);
    float cinv = 1.f / cs;
    for (int s = 0; s < SS; ++s) PbT[s * SS + j] = __expf(tr[s * SS + j] - cm) * cinv;
    // forward: row-j stats
    float rm = -1e30f;
    for (int k = 0; k < SS; ++k) rm = fmaxf(rm, tr[j * SS + k]);
    float rs = 0.f;
    for (int k = 0; k < SS; ++k) rs += __expf(tr[j * SS + k] - rm);
    float rinv = 1.f / rs;
    for (int k = 0; k < SS; ++k) PfT[k * SS + j] = __expf(tr[j * SS + k] - rm) * rinv;
}

// ---------------------------------------------------------------------------
// Convert w1 (512x64) and w2 (128x512) fp32 -> bf16
// ---------------------------------------------------------------------------
__global__ void conv_w(const float* __restrict__ w1, const float* __restrict__ w2,
                       ushort* __restrict__ w1b, ushort* __restrict__ w2b) {
    int i = blockIdx.x * 256 + threadIdx.x;
    const int N1 = HH * DD;            // 32768
    const int N2 = SS * HH;            // 65536
    if (i < N1) w1b[i] = f2bfu(w1[i]);
    else if (i < N1 + N2) w2b[i - N1] = f2bfu(w2[i - N1]);
}

// ---------------------------------------------------------------------------
// Fused MLP: emit[b][t][s] (bf16) = relu(obs@W1^T + b1) @ W2^T + b2
// One WG = 256 threads (4 waves) handles 32 consecutive t-rows of one b.
// GEMM1: H = A(32x64) @ W1^T (->512), per wave 128 N-cols.
// GEMM2 computed transposed: eT = W2 @ H^T, per wave 32 s-rows.
// ---------------------------------------------------------------------------
#define MLP_ROWS 32
__global__ __launch_bounds__(256) void mlp_kernel(
    const float* __restrict__ obs, const ushort* __restrict__ w1b,
    const ushort* __restrict__ w2b, const float* __restrict__ b1,
    const float* __restrict__ b2, ushort* __restrict__ emitb) {
    __shared__ __align__(16) ushort Alds[MLP_ROWS][72];   // 64 k + pad (stride 36 dw = 4 mod 32)
    __shared__ __align__(16) ushort Hlds[MLP_ROWS][520];  // 512 k + pad (stride 260 dw = 4 mod 32)

    int wg = blockIdx.x;                  // 32 * 128 = 4096
    int bb = wg >> 7;                     // /128 tiles per batch
    int t0 = (wg & 127) * MLP_ROWS;
    int tid = threadIdx.x;
    int lane = tid & 63, wv = tid >> 6;
    int lhi = lane >> 4, llo = lane & 15;

    // stage obs tile -> bf16 LDS (32x64)
    {
        int r = tid >> 3, c0 = (tid & 7) * 8;
        const float* src = obs + ((size_t)bb * TT + t0 + r) * DD + c0;
        float4 v0 = *(const float4*)(src);
        float4 v1 = *(const float4*)(src + 4);
        Alds[r][c0 + 0] = f2bfu(v0.x); Alds[r][c0 + 1] = f2bfu(v0.y);
        Alds[r][c0 + 2] = f2bfu(v0.z); Alds[r][c0 + 3] = f2bfu(v0.w);
        Alds[r][c0 + 4] = f2bfu(v1.x); Alds[r][c0 + 5] = f2bfu(v1.y);
        Alds[r][c0 + 6] = f2bfu(v1.z); Alds[r][c0 + 7] = f2bfu(v1.w);
    }
    __syncthreads();

    // GEMM1: acc1[mi 0..1][ni 0..7]; wave wv covers h-cols [wv*128, wv*128+128)
    f32x4 acc1[2][8];
#pragma unroll
    for (int mi = 0; mi < 2; ++mi)
#pragma unroll
        for (int ni = 0; ni < 8; ++ni) acc1[mi][ni] = (f32x4){0.f, 0.f, 0.f, 0.f};
    int nw0 = wv * 128;
#pragma unroll
    for (int kt = 0; kt < 2; ++kt) {
        s16x8 af[2];
#pragma unroll
        for (int mi = 0; mi < 2; ++mi)
            af[mi] = *(const s16x8*)(&Alds[mi * 16 + llo][kt * 32 + lhi * 8]);
#pragma unroll
        for (int ni = 0; ni < 8; ++ni) {
            int n = nw0 + ni * 16 + llo;
            s16x8 bf = *(const s16x8*)(w1b + n * DD + kt * 32 + lhi * 8);
#pragma unroll
            for (int mi = 0; mi < 2; ++mi)
                acc1[mi][ni] = __builtin_amdgcn_mfma_f32_16x16x32_bf16(af[mi], bf, acc1[mi][ni], 0, 0, 0);
        }
    }
    // epilogue 1: +b1, relu, -> Hlds bf16
#pragma unroll
    for (int ni = 0; ni < 8; ++ni) {
        int n = nw0 + ni * 16 + llo;
        float b1v = b1[n];
#pragma unroll
        for (int mi = 0; mi < 2; ++mi) {
#pragma unroll
            for (int r = 0; r < 4; ++r) {
                float hv = fmaxf(acc1[mi][ni][r] + b1v, 0.f);
                Hlds[mi * 16 + lhi * 4 + r][n] = f2bfu(hv);
            }
        }
    }
    __syncthreads();

    // GEMM2 (transposed): eT[128 s][32 t]; wave wv covers s in [wv*32, wv*32+32)
    f32x4 acc2[2][2];
#pragma unroll
    for (int si = 0; si < 2; ++si)
#pragma unroll
        for (int nt = 0; nt < 2; ++nt) acc2[si][nt] = (f32x4){0.f, 0.f, 0.f, 0.f};
    int s0 = wv * 32;
#pragma unroll
    for (int kt = 0; kt < 16; ++kt) {
        s16x8 hf[2];
#pragma unroll
        for (int nt = 0; nt < 2; ++nt)  // B-frag: col=t=nt*16+llo, k=kt*32+lhi*8
            hf[nt] = *(const s16x8*)(&Hlds[nt * 16 + llo][kt * 32 + lhi * 8]);
#pragma unroll
        for (int si = 0; si < 2; ++si) {
            int srow = s0 + si * 16 + llo;  // A-frag: row=s, k
            s16x8 wf = *(const s16x8*)(w2b + srow * HH + kt * 32 + lhi * 8);
#pragma unroll
            for (int nt = 0; nt < 2; ++nt)
                acc2[si][nt] = __builtin_amdgcn_mfma_f32_16x16x32_bf16(wf, hf[nt], acc2[si][nt], 0, 0, 0);
        }
    }
    // epilogue 2: +b2 -> emit[b][t][s] bf16 (4 consecutive s per lane -> 8B store)
#pragma unroll
    for (int si = 0; si < 2; ++si) {
        int sbase = s0 + si * 16 + lhi * 4;
        float4 b2v = *(const float4*)(b2 + sbase);
#pragma unroll
        for (int nt = 0; nt < 2; ++nt) {
            int tl = nt * 16 + llo;
            ushort* dst = emitb + ((size_t)bb * TT + t0 + tl) * SS + sbase;
            s16x4 pk;
            pk[0] = (short)f2bfu(acc2[si][nt][0] + b2v.x);
            pk[1] = (short)f2bfu(acc2[si][nt][1] + b2v.y);
            pk[2] = (short)f2bfu(acc2[si][nt][2] + b2v.z);
            pk[3] = (short)f2bfu(acc2[si][nt][3] + b2v.w);
            *(s16x4*)dst = pk;
        }
    }
}

// ---------------------------------------------------------------------------
// Chunked scans. One WG = 128 threads = one (b, dir, chunk).
// thread s owns state s; P column s in 128 VGPRs; p broadcast via LDS;
// rescale offset m = alpha[state 0] broadcast through the per-step barrier.
// Chunks warm up CH_W steps from zero-init (additive offset cancels in the
// final per-(t,b) softmax; Hilbert contraction kills the rest).
// ---------------------------------------------------------------------------
__global__ __launch_bounds__(128) void scan_kernel(
    const ushort* __restrict__ emitb, const float* __restrict__ PfT,
    const float* __restrict__ PbT, float* __restrict__ galpha,
    float* __restrict__ gbeta) {
    int wg = blockIdx.x;            // 32 b * 2 dir * 16 chunks = 1024
    int c = wg & (NCHUNK - 1);
    int dir = (wg >> 4) & 1;        // 0 = forward, 1 = backward
    int bb = wg >> 5;
    int s = threadIdx.x;

    const float* PT = dir ? PbT : PfT;
    f32x4 pc[32];
#pragma unroll
    for (int i = 0; i < 32; ++i) pc[i] = *(const f32x4*)(PT + s * SS + i * 4);

    __shared__ __align__(16) float pbuf[2][SS];
    __shared__ float mslot[2];

    int warm = (dir == 0) ? (c > 0 ? CH_W : 0) : (c < NCHUNK - 1 ? CH_W : 0);
    int nstep = CH_L + warm;
    int tfirst = (dir == 0) ? c * CH_L - warm : c * CH_L + CH_L - 1 + warm;
    intptr_t estep = (dir == 0) ? (intptr_t)SS : -(intptr_t)SS;

    const ushort* erow = emitb + ((size_t)bb * TT + tfirst) * SS + s;
    float* outp = ((dir == 0) ? galpha : gbeta) + ((size_t)bb * TT + tfirst) * SS + s;

    float alpha = 0.f, m = 0.f;
    float ecur = bfu2f(erow[0]);

    for (int v = 0; v < nstep; ++v) {
        float p = __expf(fminf(alpha - m, 60.f));
        pbuf[v & 1][s] = p;
        if (s == 0) mslot[v & 1] = alpha;
        __syncthreads();
        float mnext = mslot[v & 1];                       // alpha_{v-1}[0]
        ushort enb = erow[(intptr_t)(v + 1) * estep];     // prefetch (1-past stays in ws)
        const float* pb = pbuf[v & 1];
        float q0 = 0.f, q1 = 0.f, q2 = 0.f, q3 = 0.f;
#pragma unroll
        for (int i = 0; i < 32; ++i) {
            f32x4 pp = *(const f32x4*)(pb + i * 4);
            q0 = fmaf(pp.x, pc[i].x, q0);
            q1 = fmaf(pp.y, pc[i].y, q1);
            q2 = fmaf(pp.z, pc[i].z, q2);
            q3 = fmaf(pp.w, pc[i].w, q3);
        }
        alpha = m + __logf((q0 + q1) + (q2 + q3)) + ecur;
        if (v >= warm) outp[(intptr_t)v * estep] = alpha;
        m = mnext;
        ecur = bfu2f(enb);
    }
}

// ---------------------------------------------------------------------------
// Combine: out[b][t][s] = softmax_s(alpha + beta)  (log_Z cancels in softmax)
// One wave per (b,t) row; 2 states per lane.
// ---------------------------------------------------------------------------
__global__ __launch_bounds__(256) void combine_kernel(
    const float* __restrict__ galpha, const float* __restrict__ gbeta,
    float* __restrict__ out) {
    int row = blockIdx.x * 4 + (threadIdx.x >> 6);  // b*T + t
    int lane = threadIdx.x & 63;
    size_t base = (size_t)row * SS + lane * 2;
    float2 a = *(const float2*)(galpha + base);
    float2 b = *(const float2*)(gbeta + base);
    float g0 = a.x + b.x, g1 = a.y + b.y;
    float mx = fmaxf(g0, g1);
#pragma unroll
    for (int off = 32; off; off >>= 1) mx = fmaxf(mx, __shfl_xor(mx, off));
    float e0 = __expf(g0 - mx), e1 = __expf(g1 - mx);
    float ssum = e0 + e1;
#pragma unroll
    for (int off = 32; off; off >>= 1) ssum += __shfl_xor(ssum, off);
    float inv = 1.f / ssum;
    float2 o; o.x = e0 * inv; o.y = e1 * inv;
    *(float2*)(out + base) = o;
}

// ---------------------------------------------------------------------------
extern "C" void kernel_launch(void* const* d_in, const int* in_sizes, int n_in,
                              void* d_out, int out_size, void* d_ws, size_t ws_size,
                              hipStream_t stream) {
    const float* obs = (const float*)d_in[0];
    const float* trans = (const float*)d_in[1];
    const float* w1 = (const float*)d_in[2];
    const float* b1 = (const float*)d_in[3];
    const float* w2 = (const float*)d_in[4];
    const float* b2 = (const float*)d_in[5];
    // d_in[6] init_logits: unused by the reference computation

    char* ws = (char*)d_ws;
    float* PfT = (float*)(ws);                         // 64 KB
    float* PbT = (float*)(ws + 65536);                 // 64 KB
    ushort* w1b = (ushort*)(ws + 131072);              // 64 KB
    ushort* w2b = (ushort*)(ws + 196608);              // 128 KB
    ushort* emitb = (ushort*)(ws + 327680);            // 32 MB bf16 emissions
    float* galpha = (float*)(ws + 327680 + 33554432);  // 64 MB
    float* gbeta = (float*)(ws + 327680 + 33554432 + 67108864);  // 64 MB

    prep_trans<<<1, 128, 0, stream>>>(trans, PfT, PbT);
    conv_w<<<384, 256, 0, stream>>>(w1, w2, w1b, w2b);
    mlp_kernel<<<BB * (TT / MLP_ROWS), 256, 0, stream>>>(obs, w1b, w2b, b1, b2, emitb);
    scan_kernel<<<BB * 2 * NCHUNK, 128, 0, stream>>>(emitb, PfT, PbT, galpha, gbeta);
    combine_kernel<<<(BB * TT) / 4, 256, 0, stream>>>(galpha, gbeta, (float*)d_out);
}